// Round 1
// baseline (598.436 us; speedup 1.0000x reference)
//
#include <hip/hip_runtime.h>
#include <hip/hip_bf16.h>
#include <stdint.h>

#define DEVFN static __device__ __forceinline__

typedef __bf16 bf16x8 __attribute__((ext_vector_type(8)));
typedef float f32x4 __attribute__((ext_vector_type(4)));

DEVFN unsigned short f2bf(float f) {
  // round-to-nearest-even f32 -> bf16
  unsigned int u = __float_as_uint(f);
  u += 0x7FFFu + ((u >> 16) & 1u);
  return (unsigned short)(u >> 16);
}

DEVFN float softplus_f(float s) {
  // log1p(exp(s)), numerically stable
  return fmaxf(s, 0.0f) + log1pf(__expf(-fabsf(s)));
}

DEVFN void load_lds16(const void* g, void* l) {
  // async global->LDS, 16B per lane; LDS dest is wave-uniform base + lane*16
  __builtin_amdgcn_global_load_lds(
      (const __attribute__((address_space(1))) void*)g,
      (__attribute__((address_space(3))) void*)l, 16, 0, 0);
}

// ---------------- elementwise: A = mW + softplus(sW)*zW  (fp32 -> bf16) ----
__global__ void fuse_w_kernel(const float* __restrict__ m, const float* __restrict__ s,
                              const float* __restrict__ z, unsigned short* __restrict__ o,
                              int n4) {
  int stride = gridDim.x * blockDim.x;
  for (int i = blockIdx.x * blockDim.x + threadIdx.x; i < n4; i += stride) {
    float4 mv = reinterpret_cast<const float4*>(m)[i];
    float4 sv = reinterpret_cast<const float4*>(s)[i];
    float4 zv = reinterpret_cast<const float4*>(z)[i];
    ushort4 ov;
    ov.x = f2bf(fmaf(softplus_f(sv.x), zv.x, mv.x));
    ov.y = f2bf(fmaf(softplus_f(sv.y), zv.y, mv.y));
    ov.z = f2bf(fmaf(softplus_f(sv.z), zv.z, mv.z));
    ov.w = f2bf(fmaf(softplus_f(sv.w), zv.w, mv.w));
    reinterpret_cast<ushort4*>(o)[i] = ov;
  }
}

// ---------------- bias: b = mb + softplus(sb)*zb  (fp32) -------------------
__global__ void bias_kernel(const float* __restrict__ m, const float* __restrict__ s,
                            const float* __restrict__ z, float* __restrict__ o, int n) {
  int i = blockIdx.x * blockDim.x + threadIdx.x;
  if (i < n) o[i] = fmaf(softplus_f(s[i]), z[i], m[i]);
}

// ---------------- x fp32 -> bf16 -------------------------------------------
__global__ void xconv_kernel(const float* __restrict__ x, unsigned short* __restrict__ o,
                             int n4) {
  int stride = gridDim.x * blockDim.x;
  for (int i = blockIdx.x * blockDim.x + threadIdx.x; i < n4; i += stride) {
    float4 v = reinterpret_cast<const float4*>(x)[i];
    ushort4 ov;
    ov.x = f2bf(v.x); ov.y = f2bf(v.y); ov.z = f2bf(v.z); ov.w = f2bf(v.w);
    reinterpret_cast<ushort4*>(o)[i] = ov;
  }
}

// ---------------- GEMM: C[M,N] = X[M,K] @ W[N,K]^T + bias, optional ReLU ---
// m97 structure: 128x128 tile, BK=32, 4 waves (2x2), each wave 64x64 out
// (4x4 fragments of mfma_f32_16x16x32_bf16). global_load_lds width-16
// staging, 2-barrier K-loop.
template <int RELU, int OUTBF16>
__global__ void gemm_bt_kernel(const unsigned short* __restrict__ X,
                               const unsigned short* __restrict__ W,
                               const float* __restrict__ bias,
                               void* __restrict__ out,
                               int M, int N, int K) {
  __shared__ __align__(16) unsigned short sA[128 * 32];
  __shared__ __align__(16) unsigned short sB[128 * 32];

  const int tid  = threadIdx.x;
  const int lane = tid & 63;
  const int wv   = tid >> 6;          // wave 0..3
  const int wr   = wv >> 1;           // wave row (0..1)
  const int wc   = wv & 1;            // wave col (0..1)
  const int row0 = blockIdx.y * 128;
  const int col0 = blockIdx.x * 128;

  // ---- staging addresses: tile is [128 rows][32 k] bf16 = 8KB = 512x16B chunks
  // wave w stages chunks [w*128, w*128+128): 2 calls of 64 lanes x 16B
  const int c0    = wv * 128 + lane;   // chunk index, call 0
  const int arow  = c0 >> 2;           // 4 chunks per 64B row
  const int acolb = (c0 & 3) * 16;     // byte offset within row
  const size_t ldx = (size_t)K * 2;    // row stride in bytes
  const char* pA0 = (const char*)X + (size_t)(row0 + arow) * ldx + acolb;
  const char* pA1 = pA0 + 16 * ldx;    // chunk +64 -> row +16
  const char* pB0 = (const char*)W + (size_t)(col0 + arow) * ldx + acolb;
  const char* pB1 = pB0 + 16 * ldx;
  char* lA0 = (char*)sA + wv * 2048;
  char* lA1 = lA0 + 1024;
  char* lB0 = (char*)sB + wv * 2048;
  char* lB1 = lB0 + 1024;

  // ---- fragment read offsets (bytes) within LDS tile
  const int l15 = lane & 15;
  const int kg  = lane >> 4;           // k-group 0..3 (8 elems each)
  int aoff[4], boff[4];
#pragma unroll
  for (int i = 0; i < 4; ++i)
    aoff[i] = ((wr * 64 + i * 16 + l15) * 32 + kg * 8) * 2;
#pragma unroll
  for (int j = 0; j < 4; ++j)
    boff[j] = ((wc * 64 + j * 16 + l15) * 32 + kg * 8) * 2;

  f32x4 acc[4][4];
#pragma unroll
  for (int i = 0; i < 4; ++i)
#pragma unroll
    for (int j = 0; j < 4; ++j)
      acc[i][j] = (f32x4){0.f, 0.f, 0.f, 0.f};

  const int nk = K >> 5;
  for (int kt = 0; kt < nk; ++kt) {
    const size_t kb = (size_t)kt * 64;   // 32 k-elems * 2B
    __syncthreads();                     // prev compute done reading LDS
    load_lds16(pA0 + kb, lA0);
    load_lds16(pA1 + kb, lA1);
    load_lds16(pB0 + kb, lB0);
    load_lds16(pB1 + kb, lB1);
    __syncthreads();                     // vmcnt(0) drains staging

    bf16x8 af[4], bfv[4];
#pragma unroll
    for (int i = 0; i < 4; ++i)
      af[i] = *(const bf16x8*)((const char*)sA + aoff[i]);
#pragma unroll
    for (int j = 0; j < 4; ++j)
      bfv[j] = *(const bf16x8*)((const char*)sB + boff[j]);
#pragma unroll
    for (int i = 0; i < 4; ++i)
#pragma unroll
      for (int j = 0; j < 4; ++j)
        acc[i][j] = __builtin_amdgcn_mfma_f32_16x16x32_bf16(af[i], bfv[j], acc[i][j], 0, 0, 0);
  }

  // ---- epilogue: bias + optional ReLU; D layout col=lane&15, row=(lane>>4)*4+r
  float bv[4];
#pragma unroll
  for (int j = 0; j < 4; ++j) bv[j] = bias[col0 + wc * 64 + j * 16 + l15];

  const int rbase = row0 + wr * 64 + kg * 4;
  const int cbase = col0 + wc * 64 + l15;
#pragma unroll
  for (int i = 0; i < 4; ++i) {
#pragma unroll
    for (int j = 0; j < 4; ++j) {
#pragma unroll
      for (int r = 0; r < 4; ++r) {
        float v = acc[i][j][r] + bv[j];
        if (RELU) v = fmaxf(v, 0.0f);
        const size_t idx = (size_t)(rbase + i * 16 + r) * N + (cbase + j * 16);
        if (OUTBF16) ((unsigned short*)out)[idx] = f2bf(v);
        else         ((float*)out)[idx] = v;
      }
    }
  }
}

// ---------------------------------------------------------------------------
extern "C" void kernel_launch(void* const* d_in, const int* in_sizes, int n_in,
                              void* d_out, int out_size, void* d_ws, size_t ws_size,
                              hipStream_t stream) {
  const float* x   = (const float*)d_in[0];
  const float* mW0 = (const float*)d_in[1];
  const float* sW0 = (const float*)d_in[2];
  const float* zW0 = (const float*)d_in[3];
  const float* mb0 = (const float*)d_in[4];
  const float* sb0 = (const float*)d_in[5];
  const float* zb0 = (const float*)d_in[6];
  const float* mW1 = (const float*)d_in[7];
  const float* sW1 = (const float*)d_in[8];
  const float* zW1 = (const float*)d_in[9];
  const float* mb1 = (const float*)d_in[10];
  const float* sb1 = (const float*)d_in[11];
  const float* zb1 = (const float*)d_in[12];
  const float* mW2 = (const float*)d_in[13];
  const float* sW2 = (const float*)d_in[14];
  const float* zW2 = (const float*)d_in[15];
  const float* mb2 = (const float*)d_in[16];
  const float* sb2 = (const float*)d_in[17];
  const float* zb2 = (const float*)d_in[18];

  char* ws = (char*)d_ws;
  size_t off = 0;
  auto alloc = [&](size_t bytes) {
    char* p = ws + off;
    off += (bytes + 255) & ~(size_t)255;
    return p;
  };
  unsigned short* xb = (unsigned short*)alloc(8192ull * 1024 * 2);
  unsigned short* A0 = (unsigned short*)alloc(4096ull * 1024 * 2);
  unsigned short* A1 = (unsigned short*)alloc(4096ull * 4096 * 2);
  unsigned short* A2 = (unsigned short*)alloc(1024ull * 4096 * 2);
  unsigned short* h1 = (unsigned short*)alloc(8192ull * 4096 * 2);
  unsigned short* h2 = (unsigned short*)alloc(8192ull * 4096 * 2);
  float* b0 = (float*)alloc(4096 * 4);
  float* b1 = (float*)alloc(4096 * 4);
  float* b2 = (float*)alloc(1024 * 4);

  // weight + bias materialization, x conversion
  fuse_w_kernel<<<2048, 256, 0, stream>>>(mW0, sW0, zW0, A0, (4096 * 1024) / 4);
  fuse_w_kernel<<<2048, 256, 0, stream>>>(mW1, sW1, zW1, A1, (4096 * 4096) / 4);
  fuse_w_kernel<<<2048, 256, 0, stream>>>(mW2, sW2, zW2, A2, (1024 * 4096) / 4);
  xconv_kernel<<<2048, 256, 0, stream>>>(x, xb, (8192 * 1024) / 4);
  bias_kernel<<<16, 256, 0, stream>>>(mb0, sb0, zb0, b0, 4096);
  bias_kernel<<<16, 256, 0, stream>>>(mb1, sb1, zb1, b1, 4096);
  bias_kernel<<<4, 256, 0, stream>>>(mb2, sb2, zb2, b2, 1024);

  // layer 0: [8192,1024] @ [4096,1024]^T -> relu -> h1 bf16
  dim3 g01(4096 / 128, 8192 / 128);
  gemm_bt_kernel<1, 1><<<g01, 256, 0, stream>>>(xb, A0, b0, h1, 8192, 4096, 1024);
  // layer 1: [8192,4096] @ [4096,4096]^T -> relu -> h2 bf16
  gemm_bt_kernel<1, 1><<<g01, 256, 0, stream>>>(h1, A1, b1, h2, 8192, 4096, 4096);
  // layer 2: [8192,4096] @ [1024,4096]^T -> d_out fp32
  dim3 g2(1024 / 128, 8192 / 128);
  gemm_bt_kernel<0, 0><<<g2, 256, 0, stream>>>(h2, A2, b2, d_out, 8192, 1024, 4096);
}

// Round 2
// 548.214 us; speedup vs baseline: 1.0916x; 1.0916x over previous
//
#include <hip/hip_runtime.h>
#include <hip/hip_bf16.h>
#include <stdint.h>

#define DEVFN static __device__ __forceinline__

typedef __bf16 bf16x8 __attribute__((ext_vector_type(8)));
typedef float f32x4 __attribute__((ext_vector_type(4)));

DEVFN unsigned short f2bf(float f) {
  unsigned int u = __float_as_uint(f);
  u += 0x7FFFu + ((u >> 16) & 1u);
  return (unsigned short)(u >> 16);
}

DEVFN float softplus_f(float s) {
  return fmaxf(s, 0.0f) + log1pf(__expf(-fabsf(s)));
}

DEVFN void load_lds16(const void* g, void* l) {
  __builtin_amdgcn_global_load_lds(
      (const __attribute__((address_space(1))) void*)g,
      (__attribute__((address_space(3))) void*)l, 16, 0, 0);
}

// ---------------- elementwise: A = mW + softplus(sW)*zW  (fp32 -> bf16) ----
__global__ void fuse_w_kernel(const float* __restrict__ m, const float* __restrict__ s,
                              const float* __restrict__ z, unsigned short* __restrict__ o,
                              int n4) {
  int stride = gridDim.x * blockDim.x;
  for (int i = blockIdx.x * blockDim.x + threadIdx.x; i < n4; i += stride) {
    float4 mv = reinterpret_cast<const float4*>(m)[i];
    float4 sv = reinterpret_cast<const float4*>(s)[i];
    float4 zv = reinterpret_cast<const float4*>(z)[i];
    ushort4 ov;
    ov.x = f2bf(fmaf(softplus_f(sv.x), zv.x, mv.x));
    ov.y = f2bf(fmaf(softplus_f(sv.y), zv.y, mv.y));
    ov.z = f2bf(fmaf(softplus_f(sv.z), zv.z, mv.z));
    ov.w = f2bf(fmaf(softplus_f(sv.w), zv.w, mv.w));
    reinterpret_cast<ushort4*>(o)[i] = ov;
  }
}

// ---------------- all three biases in one launch ---------------------------
__global__ void bias_all_kernel(const float* __restrict__ mb0, const float* __restrict__ sb0,
                                const float* __restrict__ zb0,
                                const float* __restrict__ mb1, const float* __restrict__ sb1,
                                const float* __restrict__ zb1,
                                const float* __restrict__ mb2, const float* __restrict__ sb2,
                                const float* __restrict__ zb2,
                                float* __restrict__ b0, float* __restrict__ b1,
                                float* __restrict__ b2) {
  int i = blockIdx.x * blockDim.x + threadIdx.x;
  if (i < 4096) {
    b0[i] = fmaf(softplus_f(sb0[i]), zb0[i], mb0[i]);
  } else if (i < 8192) {
    int k = i - 4096;
    b1[k] = fmaf(softplus_f(sb1[k]), zb1[k], mb1[k]);
  } else if (i < 9216) {
    int k = i - 8192;
    b2[k] = fmaf(softplus_f(sb2[k]), zb2[k], mb2[k]);
  }
}

// ---------------- x fp32 -> bf16 -------------------------------------------
__global__ void xconv_kernel(const float* __restrict__ x, unsigned short* __restrict__ o,
                             int n4) {
  int stride = gridDim.x * blockDim.x;
  for (int i = blockIdx.x * blockDim.x + threadIdx.x; i < n4; i += stride) {
    float4 v = reinterpret_cast<const float4*>(x)[i];
    ushort4 ov;
    ov.x = f2bf(v.x); ov.y = f2bf(v.y); ov.z = f2bf(v.z); ov.w = f2bf(v.w);
    reinterpret_cast<ushort4*>(o)[i] = ov;
  }
}

// ===========================================================================
// 256x256 tile, BK=32, 8 waves (2M x 4N), phase-interleaved counted-vmcnt
// pipeline. LDS = 8 slots x 16KB (ring of 4 per operand, stage distance 2
// tiles => writes never touch slots being read; no latency assumption).
// Per tile: 2 phases x {ds_reads || 1 half-tile stage -> bar -> lgkmcnt(0)
// -> 16 MFMA -> bar}; vmcnt(4) once per tile (never 0 in main loop).
// [256][32] bf16 LDS rows = 64B => wave's frag ds_read_b128 pattern is a
// contiguous 1KB block => natively bank-conflict-free (no swizzle needed).
// ===========================================================================
template <int RELU, int OUTBF16>
__global__ __launch_bounds__(512, 2) void gemm256_kernel(
    const unsigned short* __restrict__ X, const unsigned short* __restrict__ W,
    const float* __restrict__ bias, void* __restrict__ out,
    int M, int N, int K) {
  __shared__ __align__(16) unsigned short lds[65536];  // 128 KiB

  const int tid  = threadIdx.x;
  const int lane = tid & 63;
  const int wv   = tid >> 6;        // 0..7
  const int wm   = wv >> 2;         // 0..1 (M half)
  const int wn   = wv & 3;          // 0..3 (N quarter)
  const int row0 = blockIdx.y * 256;
  const int col0 = blockIdx.x * 256;
  const size_t ldb = (size_t)K * 2; // row stride bytes

  // staging: half-tile (16KB) = 1024 x 16B chunks; wave wv, load l covers
  // chunks l*512 + wv*64 + lane. chunk c -> row c>>2, colbyte (c&3)*16.
  const int cA = wv * 64 + lane;
  const char* srcA = (const char*)X + (size_t)(row0 + (cA >> 2)) * ldb + (cA & 3) * 16;
  const char* srcB = (const char*)W + (size_t)(col0 + (cA >> 2)) * ldb + (cA & 3) * 16;
  char* ldsb = (char*)lds;
  const int dstOff = wv * 1024;     // wave-uniform LDS dest base (bytes)

  auto stageA = [&](int tt) {
    char* d = ldsb + (tt & 3) * 16384 + dstOff;
    const char* s = srcA + (size_t)tt * 64;
    load_lds16(s, d);
    load_lds16(s + 128 * ldb, d + 8192);
  };
  auto stageB = [&](int tt) {
    char* d = ldsb + 65536 + (tt & 3) * 16384 + dstOff;
    const char* s = srcB + (size_t)tt * 64;
    load_lds16(s, d);
    load_lds16(s + 128 * ldb, d + 8192);
  };

  // fragment read indices (ushort units within a 16KB slot)
  const int l15 = lane & 15;
  const int kg  = lane >> 4;
  const int aIdx = (wm * 128 + l15) * 32 + kg * 8;
  const int bIdx = (wn * 64 + l15) * 32 + kg * 8;

  f32x4 acc[8][4];
#pragma unroll
  for (int i = 0; i < 8; ++i)
#pragma unroll
    for (int j = 0; j < 4; ++j)
      acc[i][j] = (f32x4){0.f, 0.f, 0.f, 0.f};

  const int nt = K >> 5;

  // prologue: stage tiles 0 and 1; wait until tile 0 landed (4 newest may fly)
  stageA(0); stageB(0); stageA(1); stageB(1);
  asm volatile("s_waitcnt vmcnt(4)" ::: "memory");
  __builtin_amdgcn_s_barrier();

  for (int t = 0; t < nt; ++t) {
    const int sa = (t & 3) * 8192;
    const int sb = 32768 + (t & 3) * 8192;

    // ---- phase A: read A m-frags 0-3 + all B frags; stage A(t+2) ----
    bf16x8 a0[4], b0[4];
#pragma unroll
    for (int i = 0; i < 4; ++i) a0[i] = *(const bf16x8*)&lds[sa + aIdx + i * 512];
#pragma unroll
    for (int j = 0; j < 4; ++j) b0[j] = *(const bf16x8*)&lds[sb + bIdx + j * 512];
    if (t + 2 < nt) stageA(t + 2);
    __builtin_amdgcn_s_barrier();
    asm volatile("s_waitcnt lgkmcnt(0)" ::: "memory");
    __builtin_amdgcn_sched_barrier(0);
    __builtin_amdgcn_s_setprio(1);
#pragma unroll
    for (int i = 0; i < 4; ++i)
#pragma unroll
      for (int j = 0; j < 4; ++j)
        acc[i][j] = __builtin_amdgcn_mfma_f32_16x16x32_bf16(a0[i], b0[j], acc[i][j], 0, 0, 0);
    __builtin_amdgcn_s_setprio(0);
    __builtin_amdgcn_s_barrier();

    // ---- phase B: read A m-frags 4-7 (B retained); stage B(t+2) ----
    bf16x8 a1[4];
#pragma unroll
    for (int i = 0; i < 4; ++i) a1[i] = *(const bf16x8*)&lds[sa + aIdx + (4 + i) * 512];
    if (t + 2 < nt) stageB(t + 2);
    __builtin_amdgcn_s_barrier();
    asm volatile("s_waitcnt lgkmcnt(0)" ::: "memory");
    __builtin_amdgcn_sched_barrier(0);
    __builtin_amdgcn_s_setprio(1);
#pragma unroll
    for (int i = 0; i < 4; ++i)
#pragma unroll
      for (int j = 0; j < 4; ++j)
        acc[4 + i][j] = __builtin_amdgcn_mfma_f32_16x16x32_bf16(a1[i], b0[j], acc[4 + i][j], 0, 0, 0);
    __builtin_amdgcn_s_setprio(0);
    // tile boundary: ensure tile t+1 fully landed (only A/B(t+2) may fly)
    if (t + 2 < nt)       asm volatile("s_waitcnt vmcnt(4)" ::: "memory");
    else if (t == nt - 2) asm volatile("s_waitcnt vmcnt(0)" ::: "memory");
    __builtin_amdgcn_s_barrier();
  }

  // ---- epilogue: bias + optional ReLU ----
  float bv[4];
#pragma unroll
  for (int j = 0; j < 4; ++j) bv[j] = bias[col0 + wn * 64 + j * 16 + l15];

  const int rbase = row0 + wm * 128 + kg * 4;
  const int cbase = col0 + wn * 64 + l15;
#pragma unroll
  for (int i = 0; i < 8; ++i) {
#pragma unroll
    for (int j = 0; j < 4; ++j) {
#pragma unroll
      for (int r = 0; r < 4; ++r) {
        float v = acc[i][j][r] + bv[j];
        if (RELU) v = fmaxf(v, 0.0f);
        const size_t idx = (size_t)(rbase + i * 16 + r) * N + (cbase + j * 16);
        if (OUTBF16) ((unsigned short*)out)[idx] = f2bf(v);
        else         ((float*)out)[idx] = v;
      }
    }
  }
}

// ---------------- old 128x128 m97-structure GEMM (kept for N=1024 layer) ---
template <int RELU, int OUTBF16>
__global__ void gemm_bt_kernel(const unsigned short* __restrict__ X,
                               const unsigned short* __restrict__ W,
                               const float* __restrict__ bias,
                               void* __restrict__ out,
                               int M, int N, int K) {
  __shared__ __align__(16) unsigned short sA[128 * 32];
  __shared__ __align__(16) unsigned short sB[128 * 32];

  const int tid  = threadIdx.x;
  const int lane = tid & 63;
  const int wv   = tid >> 6;
  const int wr   = wv >> 1;
  const int wc   = wv & 1;
  const int row0 = blockIdx.y * 128;
  const int col0 = blockIdx.x * 128;

  const int c0    = wv * 128 + lane;
  const int arow  = c0 >> 2;
  const int acolb = (c0 & 3) * 16;
  const size_t ldx = (size_t)K * 2;
  const char* pA0 = (const char*)X + (size_t)(row0 + arow) * ldx + acolb;
  const char* pA1 = pA0 + 16 * ldx;
  const char* pB0 = (const char*)W + (size_t)(col0 + arow) * ldx + acolb;
  const char* pB1 = pB0 + 16 * ldx;
  char* lA0 = (char*)sA + wv * 2048;
  char* lA1 = lA0 + 1024;
  char* lB0 = (char*)sB + wv * 2048;
  char* lB1 = lB0 + 1024;

  const int l15 = lane & 15;
  const int kg  = lane >> 4;
  int aoff[4], boff[4];
#pragma unroll
  for (int i = 0; i < 4; ++i)
    aoff[i] = ((wr * 64 + i * 16 + l15) * 32 + kg * 8) * 2;
#pragma unroll
  for (int j = 0; j < 4; ++j)
    boff[j] = ((wc * 64 + j * 16 + l15) * 32 + kg * 8) * 2;

  f32x4 acc[4][4];
#pragma unroll
  for (int i = 0; i < 4; ++i)
#pragma unroll
    for (int j = 0; j < 4; ++j)
      acc[i][j] = (f32x4){0.f, 0.f, 0.f, 0.f};

  const int nk = K >> 5;
  for (int kt = 0; kt < nk; ++kt) {
    const size_t kb = (size_t)kt * 64;
    __syncthreads();
    load_lds16(pA0 + kb, lA0);
    load_lds16(pA1 + kb, lA1);
    load_lds16(pB0 + kb, lB0);
    load_lds16(pB1 + kb, lB1);
    __syncthreads();

    bf16x8 af[4], bfv[4];
#pragma unroll
    for (int i = 0; i < 4; ++i)
      af[i] = *(const bf16x8*)((const char*)sA + aoff[i]);
#pragma unroll
    for (int j = 0; j < 4; ++j)
      bfv[j] = *(const bf16x8*)((const char*)sB + boff[j]);
#pragma unroll
    for (int i = 0; i < 4; ++i)
#pragma unroll
      for (int j = 0; j < 4; ++j)
        acc[i][j] = __builtin_amdgcn_mfma_f32_16x16x32_bf16(af[i], bfv[j], acc[i][j], 0, 0, 0);
  }

  float bv[4];
#pragma unroll
  for (int j = 0; j < 4; ++j) bv[j] = bias[col0 + wc * 64 + j * 16 + l15];

  const int rbase = row0 + wr * 64 + kg * 4;
  const int cbase = col0 + wc * 64 + l15;
#pragma unroll
  for (int i = 0; i < 4; ++i) {
#pragma unroll
    for (int j = 0; j < 4; ++j) {
#pragma unroll
      for (int r = 0; r < 4; ++r) {
        float v = acc[i][j][r] + bv[j];
        if (RELU) v = fmaxf(v, 0.0f);
        const size_t idx = (size_t)(rbase + i * 16 + r) * N + (cbase + j * 16);
        if (OUTBF16) ((unsigned short*)out)[idx] = f2bf(v);
        else         ((float*)out)[idx] = v;
      }
    }
  }
}

// ---------------------------------------------------------------------------
extern "C" void kernel_launch(void* const* d_in, const int* in_sizes, int n_in,
                              void* d_out, int out_size, void* d_ws, size_t ws_size,
                              hipStream_t stream) {
  const float* x   = (const float*)d_in[0];
  const float* mW0 = (const float*)d_in[1];
  const float* sW0 = (const float*)d_in[2];
  const float* zW0 = (const float*)d_in[3];
  const float* mb0 = (const float*)d_in[4];
  const float* sb0 = (const float*)d_in[5];
  const float* zb0 = (const float*)d_in[6];
  const float* mW1 = (const float*)d_in[7];
  const float* sW1 = (const float*)d_in[8];
  const float* zW1 = (const float*)d_in[9];
  const float* mb1 = (const float*)d_in[10];
  const float* sb1 = (const float*)d_in[11];
  const float* zb1 = (const float*)d_in[12];
  const float* mW2 = (const float*)d_in[13];
  const float* sW2 = (const float*)d_in[14];
  const float* zW2 = (const float*)d_in[15];
  const float* mb2 = (const float*)d_in[16];
  const float* sb2 = (const float*)d_in[17];
  const float* zb2 = (const float*)d_in[18];

  char* ws = (char*)d_ws;
  size_t off = 0;
  auto alloc = [&](size_t bytes) {
    char* p = ws + off;
    off += (bytes + 255) & ~(size_t)255;
    return p;
  };
  unsigned short* xb = (unsigned short*)alloc(8192ull * 1024 * 2);
  unsigned short* A0 = (unsigned short*)alloc(4096ull * 1024 * 2);
  unsigned short* A1 = (unsigned short*)alloc(4096ull * 4096 * 2);
  unsigned short* A2 = (unsigned short*)alloc(1024ull * 4096 * 2);
  unsigned short* h1 = (unsigned short*)alloc(8192ull * 4096 * 2);
  unsigned short* h2 = (unsigned short*)alloc(8192ull * 4096 * 2);
  float* b0 = (float*)alloc(4096 * 4);
  float* b1 = (float*)alloc(4096 * 4);
  float* b2 = (float*)alloc(1024 * 4);

  fuse_w_kernel<<<2048, 256, 0, stream>>>(mW0, sW0, zW0, A0, (4096 * 1024) / 4);
  fuse_w_kernel<<<2048, 256, 0, stream>>>(mW1, sW1, zW1, A1, (4096 * 4096) / 4);
  fuse_w_kernel<<<2048, 256, 0, stream>>>(mW2, sW2, zW2, A2, (1024 * 4096) / 4);
  xconv_kernel<<<2048, 256, 0, stream>>>(x, xb, (8192 * 1024) / 4);
  bias_all_kernel<<<36, 256, 0, stream>>>(mb0, sb0, zb0, mb1, sb1, zb1,
                                          mb2, sb2, zb2, b0, b1, b2);

  // layer 0: [8192,1024] @ [4096,1024]^T -> relu -> h1 bf16   (256^2 pipe)
  dim3 g01(4096 / 256, 8192 / 256);
  gemm256_kernel<1, 1><<<g01, 512, 0, stream>>>(xb, A0, b0, h1, 8192, 4096, 1024);
  // layer 1: [8192,4096] @ [4096,4096]^T -> relu -> h2 bf16   (256^2 pipe)
  gemm256_kernel<1, 1><<<g01, 512, 0, stream>>>(h1, A1, b1, h2, 8192, 4096, 4096);
  // layer 2: [8192,4096] @ [1024,4096]^T -> d_out fp32        (128^2, N small)
  dim3 g2(1024 / 128, 8192 / 128);
  gemm_bt_kernel<0, 0><<<g2, 256, 0, stream>>>(h2, A2, b2, d_out, 8192, 1024, 4096);
}

// Round 3
// 532.336 us; speedup vs baseline: 1.1242x; 1.0298x over previous
//
#include <hip/hip_runtime.h>
#include <hip/hip_bf16.h>
#include <stdint.h>

#define DEVFN static __device__ __forceinline__

typedef __bf16 bf16x8 __attribute__((ext_vector_type(8)));
typedef float f32x4 __attribute__((ext_vector_type(4)));

DEVFN unsigned short f2bf(float f) {
  unsigned int u = __float_as_uint(f);
  u += 0x7FFFu + ((u >> 16) & 1u);
  return (unsigned short)(u >> 16);
}

DEVFN float softplus_f(float s) {
  return fmaxf(s, 0.0f) + log1pf(__expf(-fabsf(s)));
}

DEVFN void load_lds16(const void* g, void* l) {
  __builtin_amdgcn_global_load_lds(
      (const __attribute__((address_space(1))) void*)g,
      (__attribute__((address_space(3))) void*)l, 16, 0, 0);
}

// ---------------- elementwise: A = mW + softplus(sW)*zW  (fp32 -> bf16) ----
__global__ void fuse_w_kernel(const float* __restrict__ m, const float* __restrict__ s,
                              const float* __restrict__ z, unsigned short* __restrict__ o,
                              int n4) {
  int stride = gridDim.x * blockDim.x;
  for (int i = blockIdx.x * blockDim.x + threadIdx.x; i < n4; i += stride) {
    float4 mv = reinterpret_cast<const float4*>(m)[i];
    float4 sv = reinterpret_cast<const float4*>(s)[i];
    float4 zv = reinterpret_cast<const float4*>(z)[i];
    ushort4 ov;
    ov.x = f2bf(fmaf(softplus_f(sv.x), zv.x, mv.x));
    ov.y = f2bf(fmaf(softplus_f(sv.y), zv.y, mv.y));
    ov.z = f2bf(fmaf(softplus_f(sv.z), zv.z, mv.z));
    ov.w = f2bf(fmaf(softplus_f(sv.w), zv.w, mv.w));
    reinterpret_cast<ushort4*>(o)[i] = ov;
  }
}

// ---------------- all three biases in one launch ---------------------------
__global__ void bias_all_kernel(const float* __restrict__ mb0, const float* __restrict__ sb0,
                                const float* __restrict__ zb0,
                                const float* __restrict__ mb1, const float* __restrict__ sb1,
                                const float* __restrict__ zb1,
                                const float* __restrict__ mb2, const float* __restrict__ sb2,
                                const float* __restrict__ zb2,
                                float* __restrict__ b0, float* __restrict__ b1,
                                float* __restrict__ b2) {
  int i = blockIdx.x * blockDim.x + threadIdx.x;
  if (i < 4096) {
    b0[i] = fmaf(softplus_f(sb0[i]), zb0[i], mb0[i]);
  } else if (i < 8192) {
    int k = i - 4096;
    b1[k] = fmaf(softplus_f(sb1[k]), zb1[k], mb1[k]);
  } else if (i < 9216) {
    int k = i - 8192;
    b2[k] = fmaf(softplus_f(sb2[k]), zb2[k], mb2[k]);
  }
}

// ---------------- x fp32 -> bf16 -------------------------------------------
__global__ void xconv_kernel(const float* __restrict__ x, unsigned short* __restrict__ o,
                             int n4) {
  int stride = gridDim.x * blockDim.x;
  for (int i = blockIdx.x * blockDim.x + threadIdx.x; i < n4; i += stride) {
    float4 v = reinterpret_cast<const float4*>(x)[i];
    ushort4 ov;
    ov.x = f2bf(v.x); ov.y = f2bf(v.y); ov.z = f2bf(v.z); ov.w = f2bf(v.w);
    reinterpret_cast<ushort4*>(o)[i] = ov;
  }
}

// ===========================================================================
// 256x256 tile, BK=32, 8 waves (2M x 4N), phase-interleaved counted-vmcnt
// pipeline + T2 bank swizzle.
//
// LDS tile rows are 64B (32 bf16). Unswizzled, a wave's ds_read_b128 frag
// read (8-lane groups at 64B row stride) lands on 2 bank-quads -> 4-way
// conflict (measured 2.5e7/dispatch in R2). Swizzle: 16B-chunk index
// cc ^= (row>>1)&3 -> 8 consecutive rows cover all 32 banks. Since frag
// rows step by 16 and wave bases by 64/128, (row>>1)&3 == (l15>>1)&3 is
// lane-constant (folds into the static index). Staging keeps the LDS dest
// LINEAR (global_load_lds requirement) and pre-applies the same involution
// to the per-lane GLOBAL source chunk (rule 21: both-sides-or-neither).
// ===========================================================================
template <int RELU, int OUTBF16>
__global__ __launch_bounds__(512, 2) void gemm256_kernel(
    const unsigned short* __restrict__ X, const unsigned short* __restrict__ W,
    const float* __restrict__ bias, void* __restrict__ out,
    int M, int N, int K) {
  __shared__ __align__(16) unsigned short lds[65536];  // 128 KiB

  const int tid  = threadIdx.x;
  const int lane = tid & 63;
  const int wv   = tid >> 6;        // 0..7
  const int wm   = wv >> 2;         // 0..1 (M half)
  const int wn   = wv & 3;          // 0..3 (N quarter)
  const int row0 = blockIdx.y * 256;
  const int col0 = blockIdx.x * 256;
  const size_t ldb = (size_t)K * 2; // row stride bytes

  // staging: half-tile (16KB) = 1024 x 16B chunks; wave wv covers chunks
  // wv*64+lane (+512 for the second 128 rows). chunk c -> row c>>2,
  // chunkcol c&3; source chunkcol pre-swizzled: cc ^ ((row>>1)&3).
  const int cA  = wv * 64 + lane;
  const int rS  = cA >> 2;
  const int ccS = (cA & 3) ^ ((rS >> 1) & 3);
  const char* srcA = (const char*)X + (size_t)(row0 + rS) * ldb + ccS * 16;
  const char* srcB = (const char*)W + (size_t)(col0 + rS) * ldb + ccS * 16;
  char* ldsb = (char*)lds;
  const int dstOff = wv * 1024;     // wave-uniform LDS dest base (bytes)

  auto stageA = [&](int tt) {
    char* d = ldsb + (tt & 3) * 16384 + dstOff;
    const char* s = srcA + (size_t)tt * 64;
    load_lds16(s, d);
    load_lds16(s + 128 * ldb, d + 8192);   // row+128: (r>>1)&3 unchanged
  };
  auto stageB = [&](int tt) {
    char* d = ldsb + 65536 + (tt & 3) * 16384 + dstOff;
    const char* s = srcB + (size_t)tt * 64;
    load_lds16(s, d);
    load_lds16(s + 128 * ldb, d + 8192);
  };

  // fragment read indices (ushort units within a 16KB slot), swizzled kg
  const int l15 = lane & 15;
  const int kg  = lane >> 4;
  const int kgs = kg ^ ((l15 >> 1) & 3);   // T2 swizzle, lane-constant
  const int aIdx = (wm * 128 + l15) * 32 + kgs * 8;
  const int bIdx = (wn * 64 + l15) * 32 + kgs * 8;

  f32x4 acc[8][4];
#pragma unroll
  for (int i = 0; i < 8; ++i)
#pragma unroll
    for (int j = 0; j < 4; ++j)
      acc[i][j] = (f32x4){0.f, 0.f, 0.f, 0.f};

  const int nt = K >> 5;

  // prologue: stage tiles 0 and 1; wait until tile 0 landed (4 newest may fly)
  stageA(0); stageB(0); stageA(1); stageB(1);
  asm volatile("s_waitcnt vmcnt(4)" ::: "memory");
  __builtin_amdgcn_s_barrier();

  for (int t = 0; t < nt; ++t) {
    const int sa = (t & 3) * 8192;
    const int sb = 32768 + (t & 3) * 8192;

    // ---- phase A: read A m-frags 0-3 + all B frags; stage A(t+2) ----
    bf16x8 a0[4], b0[4];
#pragma unroll
    for (int i = 0; i < 4; ++i) a0[i] = *(const bf16x8*)&lds[sa + aIdx + i * 512];
#pragma unroll
    for (int j = 0; j < 4; ++j) b0[j] = *(const bf16x8*)&lds[sb + bIdx + j * 512];
    if (t + 2 < nt) stageA(t + 2);
    __builtin_amdgcn_s_barrier();
    asm volatile("s_waitcnt lgkmcnt(0)" ::: "memory");
    __builtin_amdgcn_sched_barrier(0);
    __builtin_amdgcn_s_setprio(1);
#pragma unroll
    for (int i = 0; i < 4; ++i)
#pragma unroll
      for (int j = 0; j < 4; ++j)
        acc[i][j] = __builtin_amdgcn_mfma_f32_16x16x32_bf16(a0[i], b0[j], acc[i][j], 0, 0, 0);
    __builtin_amdgcn_s_setprio(0);
    __builtin_amdgcn_s_barrier();

    // ---- phase B: read A m-frags 4-7 (B retained); stage B(t+2) ----
    bf16x8 a1[4];
#pragma unroll
    for (int i = 0; i < 4; ++i) a1[i] = *(const bf16x8*)&lds[sa + aIdx + (4 + i) * 512];
    if (t + 2 < nt) stageB(t + 2);
    __builtin_amdgcn_s_barrier();
    asm volatile("s_waitcnt lgkmcnt(0)" ::: "memory");
    __builtin_amdgcn_sched_barrier(0);
    __builtin_amdgcn_s_setprio(1);
#pragma unroll
    for (int i = 0; i < 4; ++i)
#pragma unroll
      for (int j = 0; j < 4; ++j)
        acc[4 + i][j] = __builtin_amdgcn_mfma_f32_16x16x32_bf16(a1[i], b0[j], acc[4 + i][j], 0, 0, 0);
    __builtin_amdgcn_s_setprio(0);
    // tile boundary: ensure tile t+1 fully landed (only A/B(t+2) may fly)
    if (t + 2 < nt)       asm volatile("s_waitcnt vmcnt(4)" ::: "memory");
    else if (t == nt - 2) asm volatile("s_waitcnt vmcnt(0)" ::: "memory");
    __builtin_amdgcn_s_barrier();
  }

  // ---- epilogue: bias + optional ReLU ----
  float bv[4];
#pragma unroll
  for (int j = 0; j < 4; ++j) bv[j] = bias[col0 + wn * 64 + j * 16 + l15];

  const int rbase = row0 + wm * 128 + kg * 4;
  const int cbase = col0 + wn * 64 + l15;
#pragma unroll
  for (int i = 0; i < 8; ++i) {
#pragma unroll
    for (int j = 0; j < 4; ++j) {
#pragma unroll
      for (int r = 0; r < 4; ++r) {
        float v = acc[i][j][r] + bv[j];
        if (RELU) v = fmaxf(v, 0.0f);
        const size_t idx = (size_t)(rbase + i * 16 + r) * N + (cbase + j * 16);
        if (OUTBF16) ((unsigned short*)out)[idx] = f2bf(v);
        else         ((float*)out)[idx] = v;
      }
    }
  }
}

// ---------------- old 128x128 m97-structure GEMM (kept for N=1024 layer) ---
template <int RELU, int OUTBF16>
__global__ void gemm_bt_kernel(const unsigned short* __restrict__ X,
                               const unsigned short* __restrict__ W,
                               const float* __restrict__ bias,
                               void* __restrict__ out,
                               int M, int N, int K) {
  __shared__ __align__(16) unsigned short sA[128 * 32];
  __shared__ __align__(16) unsigned short sB[128 * 32];

  const int tid  = threadIdx.x;
  const int lane = tid & 63;
  const int wv   = tid >> 6;
  const int wr   = wv >> 1;
  const int wc   = wv & 1;
  const int row0 = blockIdx.y * 128;
  const int col0 = blockIdx.x * 128;

  const int c0    = wv * 128 + lane;
  const int arow  = c0 >> 2;
  const int acolb = (c0 & 3) * 16;
  const size_t ldx = (size_t)K * 2;
  const char* pA0 = (const char*)X + (size_t)(row0 + arow) * ldx + acolb;
  const char* pA1 = pA0 + 16 * ldx;
  const char* pB0 = (const char*)W + (size_t)(col0 + arow) * ldx + acolb;
  const char* pB1 = pB0 + 16 * ldx;
  char* lA0 = (char*)sA + wv * 2048;
  char* lA1 = lA0 + 1024;
  char* lB0 = (char*)sB + wv * 2048;
  char* lB1 = lB0 + 1024;

  const int l15 = lane & 15;
  const int kg  = lane >> 4;
  int aoff[4], boff[4];
#pragma unroll
  for (int i = 0; i < 4; ++i)
    aoff[i] = ((wr * 64 + i * 16 + l15) * 32 + kg * 8) * 2;
#pragma unroll
  for (int j = 0; j < 4; ++j)
    boff[j] = ((wc * 64 + j * 16 + l15) * 32 + kg * 8) * 2;

  f32x4 acc[4][4];
#pragma unroll
  for (int i = 0; i < 4; ++i)
#pragma unroll
    for (int j = 0; j < 4; ++j)
      acc[i][j] = (f32x4){0.f, 0.f, 0.f, 0.f};

  const int nk = K >> 5;
  for (int kt = 0; kt < nk; ++kt) {
    const size_t kb = (size_t)kt * 64;
    __syncthreads();
    load_lds16(pA0 + kb, lA0);
    load_lds16(pA1 + kb, lA1);
    load_lds16(pB0 + kb, lB0);
    load_lds16(pB1 + kb, lB1);
    __syncthreads();

    bf16x8 af[4], bfv[4];
#pragma unroll
    for (int i = 0; i < 4; ++i)
      af[i] = *(const bf16x8*)((const char*)sA + aoff[i]);
#pragma unroll
    for (int j = 0; j < 4; ++j)
      bfv[j] = *(const bf16x8*)((const char*)sB + boff[j]);
#pragma unroll
    for (int i = 0; i < 4; ++i)
#pragma unroll
      for (int j = 0; j < 4; ++j)
        acc[i][j] = __builtin_amdgcn_mfma_f32_16x16x32_bf16(af[i], bfv[j], acc[i][j], 0, 0, 0);
  }

  float bv[4];
#pragma unroll
  for (int j = 0; j < 4; ++j) bv[j] = bias[col0 + wc * 64 + j * 16 + l15];

  const int rbase = row0 + wr * 64 + kg * 4;
  const int cbase = col0 + wc * 64 + l15;
#pragma unroll
  for (int i = 0; i < 4; ++i) {
#pragma unroll
    for (int j = 0; j < 4; ++j) {
#pragma unroll
      for (int r = 0; r < 4; ++r) {
        float v = acc[i][j][r] + bv[j];
        if (RELU) v = fmaxf(v, 0.0f);
        const size_t idx = (size_t)(rbase + i * 16 + r) * N + (cbase + j * 16);
        if (OUTBF16) ((unsigned short*)out)[idx] = f2bf(v);
        else         ((float*)out)[idx] = v;
      }
    }
  }
}

// ---------------------------------------------------------------------------
extern "C" void kernel_launch(void* const* d_in, const int* in_sizes, int n_in,
                              void* d_out, int out_size, void* d_ws, size_t ws_size,
                              hipStream_t stream) {
  const float* x   = (const float*)d_in[0];
  const float* mW0 = (const float*)d_in[1];
  const float* sW0 = (const float*)d_in[2];
  const float* zW0 = (const float*)d_in[3];
  const float* mb0 = (const float*)d_in[4];
  const float* sb0 = (const float*)d_in[5];
  const float* zb0 = (const float*)d_in[6];
  const float* mW1 = (const float*)d_in[7];
  const float* sW1 = (const float*)d_in[8];
  const float* zW1 = (const float*)d_in[9];
  const float* mb1 = (const float*)d_in[10];
  const float* sb1 = (const float*)d_in[11];
  const float* zb1 = (const float*)d_in[12];
  const float* mW2 = (const float*)d_in[13];
  const float* sW2 = (const float*)d_in[14];
  const float* zW2 = (const float*)d_in[15];
  const float* mb2 = (const float*)d_in[16];
  const float* sb2 = (const float*)d_in[17];
  const float* zb2 = (const float*)d_in[18];

  char* ws = (char*)d_ws;
  size_t off = 0;
  auto alloc = [&](size_t bytes) {
    char* p = ws + off;
    off += (bytes + 255) & ~(size_t)255;
    return p;
  };
  unsigned short* xb = (unsigned short*)alloc(8192ull * 1024 * 2);
  unsigned short* A0 = (unsigned short*)alloc(4096ull * 1024 * 2);
  unsigned short* A1 = (unsigned short*)alloc(4096ull * 4096 * 2);
  unsigned short* A2 = (unsigned short*)alloc(1024ull * 4096 * 2);
  unsigned short* h1 = (unsigned short*)alloc(8192ull * 4096 * 2);
  unsigned short* h2 = (unsigned short*)alloc(8192ull * 4096 * 2);
  float* b0 = (float*)alloc(4096 * 4);
  float* b1 = (float*)alloc(4096 * 4);
  float* b2 = (float*)alloc(1024 * 4);

  fuse_w_kernel<<<2048, 256, 0, stream>>>(mW0, sW0, zW0, A0, (4096 * 1024) / 4);
  fuse_w_kernel<<<2048, 256, 0, stream>>>(mW1, sW1, zW1, A1, (4096 * 4096) / 4);
  fuse_w_kernel<<<2048, 256, 0, stream>>>(mW2, sW2, zW2, A2, (1024 * 4096) / 4);
  xconv_kernel<<<2048, 256, 0, stream>>>(x, xb, (8192 * 1024) / 4);
  bias_all_kernel<<<36, 256, 0, stream>>>(mb0, sb0, zb0, mb1, sb1, zb1,
                                          mb2, sb2, zb2, b0, b1, b2);

  // layer 0: [8192,1024] @ [4096,1024]^T -> relu -> h1 bf16   (256^2 pipe)
  dim3 g01(4096 / 256, 8192 / 256);
  gemm256_kernel<1, 1><<<g01, 512, 0, stream>>>(xb, A0, b0, h1, 8192, 4096, 1024);
  // layer 1: [8192,4096] @ [4096,4096]^T -> relu -> h2 bf16   (256^2 pipe)
  gemm256_kernel<1, 1><<<g01, 512, 0, stream>>>(h1, A1, b1, h2, 8192, 4096, 4096);
  // layer 2: [8192,4096] @ [1024,4096]^T -> d_out fp32        (128^2, N small)
  dim3 g2(1024 / 128, 8192 / 128);
  gemm_bt_kernel<0, 0><<<g2, 256, 0, stream>>>(h2, A2, b2, d_out, 8192, 1024, 4096);
}

// Round 4
// 506.989 us; speedup vs baseline: 1.1804x; 1.0500x over previous
//
#include <hip/hip_runtime.h>
#include <hip/hip_bf16.h>
#include <stdint.h>

#define DEVFN static __device__ __forceinline__

typedef __bf16 bf16x8 __attribute__((ext_vector_type(8)));
typedef float f32x4 __attribute__((ext_vector_type(4)));

DEVFN unsigned short f2bf(float f) {
  unsigned int u = __float_as_uint(f);
  u += 0x7FFFu + ((u >> 16) & 1u);
  return (unsigned short)(u >> 16);
}

DEVFN float softplus_f(float s) {
  return fmaxf(s, 0.0f) + log1pf(__expf(-fabsf(s)));
}

DEVFN void load_lds16(const void* g, void* l) {
  __builtin_amdgcn_global_load_lds(
      (const __attribute__((address_space(1))) void*)g,
      (__attribute__((address_space(3))) void*)l, 16, 0, 0);
}

// ---------------- elementwise: A = mW + softplus(sW)*zW  (fp32 -> bf16) ----
__global__ void fuse_w_kernel(const float* __restrict__ m, const float* __restrict__ s,
                              const float* __restrict__ z, unsigned short* __restrict__ o,
                              int n4) {
  int stride = gridDim.x * blockDim.x;
  for (int i = blockIdx.x * blockDim.x + threadIdx.x; i < n4; i += stride) {
    float4 mv = reinterpret_cast<const float4*>(m)[i];
    float4 sv = reinterpret_cast<const float4*>(s)[i];
    float4 zv = reinterpret_cast<const float4*>(z)[i];
    ushort4 ov;
    ov.x = f2bf(fmaf(softplus_f(sv.x), zv.x, mv.x));
    ov.y = f2bf(fmaf(softplus_f(sv.y), zv.y, mv.y));
    ov.z = f2bf(fmaf(softplus_f(sv.z), zv.z, mv.z));
    ov.w = f2bf(fmaf(softplus_f(sv.w), zv.w, mv.w));
    reinterpret_cast<ushort4*>(o)[i] = ov;
  }
}

// ---------------- all three biases in one launch ---------------------------
__global__ void bias_all_kernel(const float* __restrict__ mb0, const float* __restrict__ sb0,
                                const float* __restrict__ zb0,
                                const float* __restrict__ mb1, const float* __restrict__ sb1,
                                const float* __restrict__ zb1,
                                const float* __restrict__ mb2, const float* __restrict__ sb2,
                                const float* __restrict__ zb2,
                                float* __restrict__ b0, float* __restrict__ b1,
                                float* __restrict__ b2) {
  int i = blockIdx.x * blockDim.x + threadIdx.x;
  if (i < 4096) {
    b0[i] = fmaf(softplus_f(sb0[i]), zb0[i], mb0[i]);
  } else if (i < 8192) {
    int k = i - 4096;
    b1[k] = fmaf(softplus_f(sb1[k]), zb1[k], mb1[k]);
  } else if (i < 9216) {
    int k = i - 8192;
    b2[k] = fmaf(softplus_f(sb2[k]), zb2[k], mb2[k]);
  }
}

// ---------------- x fp32 -> bf16 -------------------------------------------
__global__ void xconv_kernel(const float* __restrict__ x, unsigned short* __restrict__ o,
                             int n4) {
  int stride = gridDim.x * blockDim.x;
  for (int i = blockIdx.x * blockDim.x + threadIdx.x; i < n4; i += stride) {
    float4 v = reinterpret_cast<const float4*>(x)[i];
    ushort4 ov;
    ov.x = f2bf(v.x); ov.y = f2bf(v.y); ov.z = f2bf(v.z); ov.w = f2bf(v.w);
    reinterpret_cast<ushort4*>(o)[i] = ov;
  }
}

// ===========================================================================
// Pipelined GEMM, BM=256, BK=32, BN = WN*64 (WN=4 -> 256, WN=2 -> 128).
// 8 waves as (8/WN) M-rows x WN N-cols; per wave: MF = 2*WN A-frags x 4
// B-frags of 16x16x32 MFMA.
//
// Per 32-K tile (ONE barrier per tile):
//   issue aF[0..HF) + bF[0..4)  (ds_read_b128, swizzled)
//   sched_barrier -- pins read-group order so counted lgkmcnt is exact
//   issue aF[HF..MF); stage tile t+2 (global_load_lds -> slot (t+2)&3)
//   lgkmcnt(HF)  -> MFMA cluster 1 (aF[HF..) drain underneath)
//   lgkmcnt(0)   -> MFMA cluster 2
//   vmcnt(LPT)   -> tile t+1 landed (t+2's LPT loads still in flight)
//   s_barrier
// Sync argument (no latency assumptions): reads touch slot t&3, stage
// writes touch (t+2)&3 (ring of 4, disjoint); the end-of-tile
// vmcnt+barrier publishes tile t+1's cooperative stage to all waves.
// No mid-tile barrier => wave drift overlaps one wave's ds_reads with
// another's MFMA (2 waves/SIMD).
//
// T2 swizzle (R3, verified): 16B-chunk cc ^= (row>>1)&3; applied to the
// per-lane GLOBAL source on stage and to the (lane-constant) kg on read.
// ===========================================================================
template <int WN, int RELU, int OUTBF16>
__global__ __launch_bounds__(512, 2) void gemm_pipe_kernel(
    const unsigned short* __restrict__ X, const unsigned short* __restrict__ W,
    const float* __restrict__ bias, void* __restrict__ out,
    int M, int N, int K) {
  constexpr int BN   = WN * 64;        // 256 or 128
  constexpr int MF   = 2 * WN;         // A-frags per wave (8 or 4)
  constexpr int HF   = MF / 2;
  constexpr int BS   = BN * 32;        // B slot size, ushorts
  __shared__ __align__(16) unsigned short lds[32768 + 4 * BS];

  const int tid  = threadIdx.x;
  const int lane = tid & 63;
  const int wv   = tid >> 6;                 // 0..7
  const int wm   = wv / WN;                  // M row of wave grid
  const int wn   = wv % WN;                  // N col of wave grid
  const int row0 = blockIdx.y * 256;
  const int col0 = blockIdx.x * BN;
  const size_t ldb = (size_t)K * 2;

  // staging: chunk c of a tile -> row c>>2, chunkcol c&3; global source
  // chunkcol pre-swizzled cc ^ ((row>>1)&3); LDS dest linear.
  const int cA  = wv * 64 + lane;            // 0..511
  const int rS  = cA >> 2;                   // 0..127
  const int ccS = (cA & 3) ^ ((rS >> 1) & 3);
  const char* srcA = (const char*)X + (size_t)(row0 + rS) * ldb + ccS * 16;
  const char* srcB = (const char*)W + (size_t)(col0 + rS) * ldb + ccS * 16;
  char* ldsb = (char*)lds;

  auto stageA = [&](int tt) {
    char* d = ldsb + (tt & 3) * 16384 + wv * 1024;
    const char* s = srcA + (size_t)tt * 64;
    load_lds16(s, d);
    load_lds16(s + 128 * ldb, d + 8192);     // rows +128: swizzle invariant
  };
  auto stageB = [&](int tt) {
    char* d = ldsb + 65536 + (tt & 3) * (BS * 2) + wv * 1024;
    const char* s = srcB + (size_t)tt * 64;
    load_lds16(s, d);
    if constexpr (WN == 4) load_lds16(s + 128 * ldb, d + 8192);
  };

  // fragment read indices (ushort units), swizzled kg (lane-constant)
  const int l15 = lane & 15;
  const int kg  = lane >> 4;
  const int kgs = kg ^ ((l15 >> 1) & 3);
  const int aIdx = (wm * (32 * WN) + l15) * 32 + kgs * 8;
  const int bIdx = (wn * 64 + l15) * 32 + kgs * 8;

  f32x4 acc[MF][4];
#pragma unroll
  for (int i = 0; i < MF; ++i)
#pragma unroll
    for (int j = 0; j < 4; ++j)
      acc[i][j] = (f32x4){0.f, 0.f, 0.f, 0.f};

  const int nt = K >> 5;

  // prologue: stage tiles 0,1; wait tile 0 (tile 1's LPT loads in flight)
  stageA(0); stageB(0); stageA(1); stageB(1);
  if constexpr (WN == 4) asm volatile("s_waitcnt vmcnt(4)" ::: "memory");
  else                   asm volatile("s_waitcnt vmcnt(3)" ::: "memory");
  __builtin_amdgcn_s_barrier();

  for (int t = 0; t < nt; ++t) {
    const int sa = (t & 3) * 8192;
    const int sb = 32768 + (t & 3) * BS;

    bf16x8 aF[MF], bF[4];
#pragma unroll
    for (int i = 0; i < HF; ++i) aF[i] = *(const bf16x8*)&lds[sa + aIdx + i * 512];
#pragma unroll
    for (int j = 0; j < 4; ++j)  bF[j] = *(const bf16x8*)&lds[sb + bIdx + j * 512];
    __builtin_amdgcn_sched_barrier(0);       // pin group order for lgkm count
#pragma unroll
    for (int i = HF; i < MF; ++i) aF[i] = *(const bf16x8*)&lds[sa + aIdx + i * 512];
    if (t + 2 < nt) { stageA(t + 2); stageB(t + 2); }

    if constexpr (WN == 4) asm volatile("s_waitcnt lgkmcnt(4)" ::: "memory");
    else                   asm volatile("s_waitcnt lgkmcnt(2)" ::: "memory");
    __builtin_amdgcn_sched_barrier(0);
    __builtin_amdgcn_s_setprio(1);
#pragma unroll
    for (int i = 0; i < HF; ++i)
#pragma unroll
      for (int j = 0; j < 4; ++j)
        acc[i][j] = __builtin_amdgcn_mfma_f32_16x16x32_bf16(aF[i], bF[j], acc[i][j], 0, 0, 0);
    __builtin_amdgcn_s_setprio(0);

    asm volatile("s_waitcnt lgkmcnt(0)" ::: "memory");
    __builtin_amdgcn_sched_barrier(0);
    __builtin_amdgcn_s_setprio(1);
#pragma unroll
    for (int i = HF; i < MF; ++i)
#pragma unroll
      for (int j = 0; j < 4; ++j)
        acc[i][j] = __builtin_amdgcn_mfma_f32_16x16x32_bf16(aF[i], bF[j], acc[i][j], 0, 0, 0);
    __builtin_amdgcn_s_setprio(0);

    // tile boundary: tile t+1 must be fully landed for every wave
    if (t + 2 < nt) {
      if constexpr (WN == 4) asm volatile("s_waitcnt vmcnt(4)" ::: "memory");
      else                   asm volatile("s_waitcnt vmcnt(3)" ::: "memory");
    } else if (t == nt - 2) {
      asm volatile("s_waitcnt vmcnt(0)" ::: "memory");
    }
    __builtin_amdgcn_s_barrier();
  }

  // ---- epilogue: bias + optional ReLU ----
  float bv[4];
#pragma unroll
  for (int j = 0; j < 4; ++j) bv[j] = bias[col0 + wn * 64 + j * 16 + l15];

  const int rbase = row0 + wm * (32 * WN) + kg * 4;
  const int cbase = col0 + wn * 64 + l15;
#pragma unroll
  for (int i = 0; i < MF; ++i) {
#pragma unroll
    for (int j = 0; j < 4; ++j) {
#pragma unroll
      for (int r = 0; r < 4; ++r) {
        float v = acc[i][j][r] + bv[j];
        if (RELU) v = fmaxf(v, 0.0f);
        const size_t idx = (size_t)(rbase + i * 16 + r) * N + (cbase + j * 16);
        if (OUTBF16) ((unsigned short*)out)[idx] = f2bf(v);
        else         ((float*)out)[idx] = v;
      }
    }
  }
}

// ---------------------------------------------------------------------------
extern "C" void kernel_launch(void* const* d_in, const int* in_sizes, int n_in,
                              void* d_out, int out_size, void* d_ws, size_t ws_size,
                              hipStream_t stream) {
  const float* x   = (const float*)d_in[0];
  const float* mW0 = (const float*)d_in[1];
  const float* sW0 = (const float*)d_in[2];
  const float* zW0 = (const float*)d_in[3];
  const float* mb0 = (const float*)d_in[4];
  const float* sb0 = (const float*)d_in[5];
  const float* zb0 = (const float*)d_in[6];
  const float* mW1 = (const float*)d_in[7];
  const float* sW1 = (const float*)d_in[8];
  const float* zW1 = (const float*)d_in[9];
  const float* mb1 = (const float*)d_in[10];
  const float* sb1 = (const float*)d_in[11];
  const float* zb1 = (const float*)d_in[12];
  const float* mW2 = (const float*)d_in[13];
  const float* sW2 = (const float*)d_in[14];
  const float* zW2 = (const float*)d_in[15];
  const float* mb2 = (const float*)d_in[16];
  const float* sb2 = (const float*)d_in[17];
  const float* zb2 = (const float*)d_in[18];

  char* ws = (char*)d_ws;
  size_t off = 0;
  auto alloc = [&](size_t bytes) {
    char* p = ws + off;
    off += (bytes + 255) & ~(size_t)255;
    return p;
  };
  unsigned short* xb = (unsigned short*)alloc(8192ull * 1024 * 2);
  unsigned short* A0 = (unsigned short*)alloc(4096ull * 1024 * 2);
  unsigned short* A1 = (unsigned short*)alloc(4096ull * 4096 * 2);
  unsigned short* A2 = (unsigned short*)alloc(1024ull * 4096 * 2);
  unsigned short* h1 = (unsigned short*)alloc(8192ull * 4096 * 2);
  unsigned short* h2 = (unsigned short*)alloc(8192ull * 4096 * 2);
  float* b0 = (float*)alloc(4096 * 4);
  float* b1 = (float*)alloc(4096 * 4);
  float* b2 = (float*)alloc(1024 * 4);

  fuse_w_kernel<<<2048, 256, 0, stream>>>(mW0, sW0, zW0, A0, (4096 * 1024) / 4);
  fuse_w_kernel<<<2048, 256, 0, stream>>>(mW1, sW1, zW1, A1, (4096 * 4096) / 4);
  fuse_w_kernel<<<2048, 256, 0, stream>>>(mW2, sW2, zW2, A2, (1024 * 4096) / 4);
  xconv_kernel<<<2048, 256, 0, stream>>>(x, xb, (8192 * 1024) / 4);
  bias_all_kernel<<<36, 256, 0, stream>>>(mb0, sb0, zb0, mb1, sb1, zb1,
                                          mb2, sb2, zb2, b0, b1, b2);

  // layer 0: [8192,1024] @ [4096,1024]^T -> relu -> h1 bf16   (BN=256)
  dim3 g01(4096 / 256, 8192 / 256);
  gemm_pipe_kernel<4, 1, 1><<<g01, 512, 0, stream>>>(xb, A0, b0, h1, 8192, 4096, 1024);
  // layer 1: [8192,4096] @ [4096,4096]^T -> relu -> h2 bf16   (BN=256)
  gemm_pipe_kernel<4, 1, 1><<<g01, 512, 0, stream>>>(h1, A1, b1, h2, 8192, 4096, 4096);
  // layer 2: [8192,4096] @ [1024,4096]^T -> d_out fp32        (BN=128, 256 blocks)
  dim3 g2(1024 / 128, 8192 / 256);
  gemm_pipe_kernel<2, 0, 0><<<g2, 512, 0, stream>>>(h2, A2, b2, d_out, 8192, 1024, 4096);
}

// Round 5
// 506.932 us; speedup vs baseline: 1.1805x; 1.0001x over previous
//
#include <hip/hip_runtime.h>
#include <hip/hip_bf16.h>
#include <stdint.h>

#define DEVFN static __device__ __forceinline__

typedef __bf16 bf16x8 __attribute__((ext_vector_type(8)));
typedef float f32x4 __attribute__((ext_vector_type(4)));

DEVFN unsigned short f2bf(float f) {
  unsigned int u = __float_as_uint(f);
  u += 0x7FFFu + ((u >> 16) & 1u);
  return (unsigned short)(u >> 16);
}

DEVFN float softplus_f(float s) {
  return fmaxf(s, 0.0f) + log1pf(__expf(-fabsf(s)));
}

DEVFN void load_lds16(const void* g, void* l) {
  __builtin_amdgcn_global_load_lds(
      (const __attribute__((address_space(1))) void*)g,
      (__attribute__((address_space(3))) void*)l, 16, 0, 0);
}

// ---------------- elementwise: A = mW + softplus(sW)*zW  (fp32 -> bf16) ----
__global__ void fuse_w_kernel(const float* __restrict__ m, const float* __restrict__ s,
                              const float* __restrict__ z, unsigned short* __restrict__ o,
                              int n4) {
  int stride = gridDim.x * blockDim.x;
  for (int i = blockIdx.x * blockDim.x + threadIdx.x; i < n4; i += stride) {
    float4 mv = reinterpret_cast<const float4*>(m)[i];
    float4 sv = reinterpret_cast<const float4*>(s)[i];
    float4 zv = reinterpret_cast<const float4*>(z)[i];
    ushort4 ov;
    ov.x = f2bf(fmaf(softplus_f(sv.x), zv.x, mv.x));
    ov.y = f2bf(fmaf(softplus_f(sv.y), zv.y, mv.y));
    ov.z = f2bf(fmaf(softplus_f(sv.z), zv.z, mv.z));
    ov.w = f2bf(fmaf(softplus_f(sv.w), zv.w, mv.w));
    reinterpret_cast<ushort4*>(o)[i] = ov;
  }
}

// ---------------- all three biases in one launch ---------------------------
__global__ void bias_all_kernel(const float* __restrict__ mb0, const float* __restrict__ sb0,
                                const float* __restrict__ zb0,
                                const float* __restrict__ mb1, const float* __restrict__ sb1,
                                const float* __restrict__ zb1,
                                const float* __restrict__ mb2, const float* __restrict__ sb2,
                                const float* __restrict__ zb2,
                                float* __restrict__ b0, float* __restrict__ b1,
                                float* __restrict__ b2) {
  int i = blockIdx.x * blockDim.x + threadIdx.x;
  if (i < 4096) {
    b0[i] = fmaf(softplus_f(sb0[i]), zb0[i], mb0[i]);
  } else if (i < 8192) {
    int k = i - 4096;
    b1[k] = fmaf(softplus_f(sb1[k]), zb1[k], mb1[k]);
  } else if (i < 9216) {
    int k = i - 8192;
    b2[k] = fmaf(softplus_f(sb2[k]), zb2[k], mb2[k]);
  }
}

// ---------------- x fp32 -> bf16 -------------------------------------------
__global__ void xconv_kernel(const float* __restrict__ x, unsigned short* __restrict__ o,
                             int n4) {
  int stride = gridDim.x * blockDim.x;
  for (int i = blockIdx.x * blockDim.x + threadIdx.x; i < n4; i += stride) {
    float4 v = reinterpret_cast<const float4*>(x)[i];
    ushort4 ov;
    ov.x = f2bf(v.x); ov.y = f2bf(v.y); ov.z = f2bf(v.z); ov.w = f2bf(v.w);
    reinterpret_cast<ushort4*>(o)[i] = ov;
  }
}

// ===========================================================================
// Pipelined GEMM, BM=256, BK=32, BN = WN*64 (WN=4 -> 256, WN=2 -> 128).
// 8 waves as (8/WN) M-rows x WN N-cols.
//
// R5: register double-buffer across K-tiles. Per iter t:
//   issue NR ds_read_b128 frags(t+1) -> nxt regs ; issue stage(t+3)
//   s_waitcnt lgkmcnt(NR)   <- cur regs (tile t, issued iter t-1) complete;
//                              the NR newest (t+1) stay in flight and drain
//                              UNDER the MFMA cluster (~1240 cyc of cover)
//   sched_barrier(0)        <- rule 18: keep MFMA below the wait
//   MFMA(t) on cur regs (setprio 1)
//   s_waitcnt vmcnt(LPT)    <- tile t+2's cooperative stage landed
//   s_barrier               <- publish t+2
// Ring-of-4 slots: read (t+1)&3, MFMA-source t&3 (reads already fenced),
// landing (t+2)&3, staging (t+3)&3 -- all distinct, so sync needs no
// latency assumptions. Counted waits are exact: each bf16x8 LDS load is
// one ds_read_b128 (only lgkm ops in loop); each wave issues LPT
// global_load_lds per tile (only vmcnt ops). Loop 2x-unrolled so frag
// buffers are statically indexed (rule 20).
//
// T2 swizzle (R3/R4, verified conflict-free): 16B-chunk cc ^= (row>>1)&3
// on the per-lane GLOBAL source at stage; kg ^= (l15>>1)&3 on read.
// ===========================================================================
template <int WN, int RELU, int OUTBF16>
__global__ __launch_bounds__(512, 2) void gemm_pipe_kernel(
    const unsigned short* __restrict__ X, const unsigned short* __restrict__ W,
    const float* __restrict__ bias, void* __restrict__ out,
    int M, int N, int K) {
  constexpr int BN  = WN * 64;         // 256 or 128
  constexpr int MF  = 2 * WN;          // A-frags per wave (8 or 4)
  constexpr int NR  = MF + 4;          // ds_reads per tile per wave
  constexpr int LPT = (WN == 4) ? 4 : 3;  // global_load_lds per tile per wave
  constexpr int BS  = BN * 32;         // B slot size, ushorts
  __shared__ __align__(16) unsigned short lds[32768 + 4 * BS];

  const int tid  = threadIdx.x;
  const int lane = tid & 63;
  const int wv   = tid >> 6;                 // 0..7
  const int wm   = wv / WN;
  const int wn   = wv % WN;
  const int row0 = blockIdx.y * 256;
  const int col0 = blockIdx.x * BN;
  const size_t ldb = (size_t)K * 2;

  // staging: chunk c -> row c>>2, chunkcol c&3; source chunkcol pre-swizzled
  const int cA  = wv * 64 + lane;
  const int rS  = cA >> 2;
  const int ccS = (cA & 3) ^ ((rS >> 1) & 3);
  const char* srcA = (const char*)X + (size_t)(row0 + rS) * ldb + ccS * 16;
  const char* srcB = (const char*)W + (size_t)(col0 + rS) * ldb + ccS * 16;
  char* ldsb = (char*)lds;

  auto stageA = [&](int tt) {
    char* d = ldsb + (tt & 3) * 16384 + wv * 1024;
    const char* s = srcA + (size_t)tt * 64;
    load_lds16(s, d);
    load_lds16(s + 128 * ldb, d + 8192);     // rows +128: swizzle invariant
  };
  auto stageB = [&](int tt) {
    char* d = ldsb + 65536 + (tt & 3) * (BS * 2) + wv * 1024;
    const char* s = srcB + (size_t)tt * 64;
    load_lds16(s, d);
    if constexpr (WN == 4) load_lds16(s + 128 * ldb, d + 8192);
  };

  const int l15 = lane & 15;
  const int kg  = lane >> 4;
  const int kgs = kg ^ ((l15 >> 1) & 3);
  const int aIdx = (wm * (32 * WN) + l15) * 32 + kgs * 8;
  const int bIdx = (wn * 64 + l15) * 32 + kgs * 8;

  f32x4 acc[MF][4];
#pragma unroll
  for (int i = 0; i < MF; ++i)
#pragma unroll
    for (int j = 0; j < 4; ++j)
      acc[i][j] = (f32x4){0.f, 0.f, 0.f, 0.f};

  auto readFrags = [&](int tt, bf16x8 (&aF)[MF], bf16x8 (&bF)[4]) {
    const int sa = (tt & 3) * 8192;
    const int sb = 32768 + (tt & 3) * BS;
#pragma unroll
    for (int i = 0; i < MF; ++i) aF[i] = *(const bf16x8*)&lds[sa + aIdx + i * 512];
#pragma unroll
    for (int j = 0; j < 4; ++j)  bF[j] = *(const bf16x8*)&lds[sb + bIdx + j * 512];
  };
  auto mfmaTile = [&](bf16x8 (&aF)[MF], bf16x8 (&bF)[4]) {
    __builtin_amdgcn_s_setprio(1);
#pragma unroll
    for (int i = 0; i < MF; ++i)
#pragma unroll
      for (int j = 0; j < 4; ++j)
        acc[i][j] = __builtin_amdgcn_mfma_f32_16x16x32_bf16(aF[i], bF[j], acc[i][j], 0, 0, 0);
    __builtin_amdgcn_s_setprio(0);
  };

  const int nt = K >> 5;
  bf16x8 aA[MF], bA[4], aB[MF], bB[4];

  // prologue: stage tiles 0,1,2; publish 0,1; preload frags(0)
  stageA(0); stageB(0); stageA(1); stageB(1); stageA(2); stageB(2);
  asm volatile("s_waitcnt vmcnt(%0)" :: "i"(LPT) : "memory");  // t0,t1 landed
  __builtin_amdgcn_s_barrier();
  readFrags(0, aA, bA);

  auto body = [&](int t, bf16x8 (&aCur)[MF], bf16x8 (&bCur)[4],
                  bf16x8 (&aNxt)[MF], bf16x8 (&bNxt)[4]) {
    readFrags(t + 1, aNxt, bNxt);
    if (t + 3 < nt) { stageA(t + 3); stageB(t + 3); }
    asm volatile("s_waitcnt lgkmcnt(%0)" :: "i"(NR) : "memory");
    __builtin_amdgcn_sched_barrier(0);
    mfmaTile(aCur, bCur);
    if (t + 3 < nt) asm volatile("s_waitcnt vmcnt(%0)" :: "i"(LPT) : "memory");
    else            asm volatile("s_waitcnt vmcnt(0)" ::: "memory");
    __builtin_amdgcn_s_barrier();  // publish t+2
  };

  for (int t = 0; t < nt - 2; t += 2) {
    body(t,     aA, bA, aB, bB);
    body(t + 1, aB, bB, aA, bA);
  }
  body(nt - 2, aA, bA, aB, bB);   // reads frags(nt-1); drains staging
  asm volatile("s_waitcnt lgkmcnt(0)" ::: "memory");
  __builtin_amdgcn_sched_barrier(0);
  mfmaTile(aB, bB);

  // ---- epilogue: bias + optional ReLU ----
  float bv[4];
#pragma unroll
  for (int j = 0; j < 4; ++j) bv[j] = bias[col0 + wn * 64 + j * 16 + l15];

  const int rbase = row0 + wm * (32 * WN) + kg * 4;
  const int cbase = col0 + wn * 64 + l15;
#pragma unroll
  for (int i = 0; i < MF; ++i) {
#pragma unroll
    for (int j = 0; j < 4; ++j) {
#pragma unroll
      for (int r = 0; r < 4; ++r) {
        float v = acc[i][j][r] + bv[j];
        if (RELU) v = fmaxf(v, 0.0f);
        const size_t idx = (size_t)(rbase + i * 16 + r) * N + (cbase + j * 16);
        if (OUTBF16) ((unsigned short*)out)[idx] = f2bf(v);
        else         ((float*)out)[idx] = v;
      }
    }
  }
}

// ---------------------------------------------------------------------------
extern "C" void kernel_launch(void* const* d_in, const int* in_sizes, int n_in,
                              void* d_out, int out_size, void* d_ws, size_t ws_size,
                              hipStream_t stream) {
  const float* x   = (const float*)d_in[0];
  const float* mW0 = (const float*)d_in[1];
  const float* sW0 = (const float*)d_in[2];
  const float* zW0 = (const float*)d_in[3];
  const float* mb0 = (const float*)d_in[4];
  const float* sb0 = (const float*)d_in[5];
  const float* zb0 = (const float*)d_in[6];
  const float* mW1 = (const float*)d_in[7];
  const float* sW1 = (const float*)d_in[8];
  const float* zW1 = (const float*)d_in[9];
  const float* mb1 = (const float*)d_in[10];
  const float* sb1 = (const float*)d_in[11];
  const float* zb1 = (const float*)d_in[12];
  const float* mW2 = (const float*)d_in[13];
  const float* sW2 = (const float*)d_in[14];
  const float* zW2 = (const float*)d_in[15];
  const float* mb2 = (const float*)d_in[16];
  const float* sb2 = (const float*)d_in[17];
  const float* zb2 = (const float*)d_in[18];

  char* ws = (char*)d_ws;
  size_t off = 0;
  auto alloc = [&](size_t bytes) {
    char* p = ws + off;
    off += (bytes + 255) & ~(size_t)255;
    return p;
  };
  unsigned short* xb = (unsigned short*)alloc(8192ull * 1024 * 2);
  unsigned short* A0 = (unsigned short*)alloc(4096ull * 1024 * 2);
  unsigned short* A1 = (unsigned short*)alloc(4096ull * 4096 * 2);
  unsigned short* A2 = (unsigned short*)alloc(1024ull * 4096 * 2);
  unsigned short* h1 = (unsigned short*)alloc(8192ull * 4096 * 2);
  unsigned short* h2 = (unsigned short*)alloc(8192ull * 4096 * 2);
  float* b0 = (float*)alloc(4096 * 4);
  float* b1 = (float*)alloc(4096 * 4);
  float* b2 = (float*)alloc(1024 * 4);

  fuse_w_kernel<<<2048, 256, 0, stream>>>(mW0, sW0, zW0, A0, (4096 * 1024) / 4);
  fuse_w_kernel<<<2048, 256, 0, stream>>>(mW1, sW1, zW1, A1, (4096 * 4096) / 4);
  fuse_w_kernel<<<2048, 256, 0, stream>>>(mW2, sW2, zW2, A2, (1024 * 4096) / 4);
  xconv_kernel<<<2048, 256, 0, stream>>>(x, xb, (8192 * 1024) / 4);
  bias_all_kernel<<<36, 256, 0, stream>>>(mb0, sb0, zb0, mb1, sb1, zb1,
                                          mb2, sb2, zb2, b0, b1, b2);

  // layer 0: [8192,1024] @ [4096,1024]^T -> relu -> h1 bf16   (BN=256)
  dim3 g01(4096 / 256, 8192 / 256);
  gemm_pipe_kernel<4, 1, 1><<<g01, 512, 0, stream>>>(xb, A0, b0, h1, 8192, 4096, 1024);
  // layer 1: [8192,4096] @ [4096,4096]^T -> relu -> h2 bf16   (BN=256)
  gemm_pipe_kernel<4, 1, 1><<<g01, 512, 0, stream>>>(h1, A1, b1, h2, 8192, 4096, 4096);
  // layer 2: [8192,4096] @ [1024,4096]^T -> d_out fp32        (BN=128, 256 blocks)
  dim3 g2(1024 / 128, 8192 / 256);
  gemm_pipe_kernel<2, 0, 0><<<g2, 512, 0, stream>>>(h2, A2, b2, d_out, 8192, 1024, 4096);
}